// Round 1
// baseline (326.979 us; speedup 1.0000x reference)
//
#include <hip/hip_runtime.h>

// LRN (buggy-keras window) on x:(64,56,56,192) fp32, NHWC.
// window for channel c: [max(c-2,0), min(2c+3, C))  -- verified vs reference algebra
// scale = (win_sum * (ALPHA/N) + 1)^BETA ; out = x / scale
// One wave per pixel: 192 channels = 3 per lane (lane, lane+64, lane+128) -> coalesced.
// Wave shfl inclusive scan x3 -> exclusive prefix cs[0..192] in LDS -> O(1) window sums.

constexpr int   C            = 192;
constexpr int   WAVES        = 4;            // waves (pixels) per block
constexpr int   BLOCK        = WAVES * 64;
constexpr float ALPHA_OVER_N = 0.0001f / 5.0f;   // 2e-5
constexpr float BETA_C       = 0.75f;

__global__ __launch_bounds__(BLOCK) void lrn_kernel(
    const float* __restrict__ x, float* __restrict__ out, int npix) {
  __shared__ float cs[WAVES][C + 1];
  const int lane = threadIdx.x & 63;
  const int wave = threadIdx.x >> 6;
  int pix = blockIdx.x * WAVES + wave;
  if (pix >= npix) pix = npix - 1;  // clamp: duplicate work keeps __syncthreads uniform

  const float* xr   = x   + (size_t)pix * C;
  float*       orow = out + (size_t)pix * C;

  const float x0 = xr[lane];
  const float x1 = xr[lane + 64];
  const float x2 = xr[lane + 128];
  const float s0 = x0 * x0, s1 = x1 * x1, s2 = x2 * x2;

  // Inclusive scans over the three 64-wide segments (wave = 64 lanes on CDNA).
  float p0 = s0, p1 = s1, p2 = s2;
#pragma unroll
  for (int off = 1; off < 64; off <<= 1) {
    const float t0 = __shfl_up(p0, off, 64);
    const float t1 = __shfl_up(p1, off, 64);
    const float t2 = __shfl_up(p2, off, 64);
    if (lane >= off) { p0 += t0; p1 += t1; p2 += t2; }
  }
  const float T0 = __shfl(p0, 63, 64);  // segment 0 total
  const float T1 = __shfl(p1, 63, 64);  // segment 1 total

  // Exclusive prefix sums cs[j] = sum of x^2 over channels [0, j)
  cs[wave][lane]       = p0 - s0;
  cs[wave][64 + lane]  = T0 + p1 - s1;
  cs[wave][128 + lane] = T0 + T1 + p2 - s2;
  if (lane == 63) cs[wave][C] = T0 + T1 + p2;
  __syncthreads();  // cross-lane LDS visibility (compiler ordering; uniform by clamp)

  const float xv0 = x0, xv1 = x1, xv2 = x2;
  const float xs[3] = {xv0, xv1, xv2};
#pragma unroll
  for (int k = 0; k < 3; ++k) {
    const int c = lane + 64 * k;
    int head = c - 2;     head = head < 0 ? 0 : head;
    int end  = 2 * c + 3; end  = end > C ? C : end;
    const float sum = cs[wave][end] - cs[wave][head];
    const float v   = fmaf(sum, ALPHA_OVER_N, 1.0f);   // v in [1, ~1.01]
    const float inv_scale = __powf(v, -BETA_C);        // fast pow: huge margin vs 0.108 thr
    orow[c] = xs[k] * inv_scale;
  }
}

extern "C" void kernel_launch(void* const* d_in, const int* in_sizes, int n_in,
                              void* d_out, int out_size, void* d_ws, size_t ws_size,
                              hipStream_t stream) {
  const float* x   = (const float*)d_in[0];
  float*       out = (float*)d_out;
  const int npix = in_sizes[0] / C;                 // 64*56*56 = 200704
  const int grid = (npix + WAVES - 1) / WAVES;      // 50176
  lrn_kernel<<<grid, BLOCK, 0, stream>>>(x, out, npix);
}

// Round 2
// 267.139 us; speedup vs baseline: 1.2240x; 1.2240x over previous
//
#include <hip/hip_runtime.h>

// LRN (buggy-keras window) on x:(64,56,56,192) fp32 NHWC.
// window for channel c: [max(c-2,0), min(2c+3, C)); scale=(sum*2e-5+1)^0.75; out=x/scale
//
// R2 design: no cross-lane shuffles (R1 was latency-bound on 18 serial ds_bpermute).
// Thread owns 16 consecutive channels; 12 threads/pixel; 16 pixels per 192-thread block.
// Register-serial prefix + LDS chunk-total stitch; swizzled cs layout j+4*(j>>5) breaks
// the 32-word gather stride (would be 12-way bank conflict -> now <=2-way, free).
// (1+e)^-0.75 via cubic binomial series (e<=~0.01 -> err <1e-8 vs thr 0.108): no transcendentals.

constexpr int   C         = 192;
constexpr int   TPP       = 12;           // threads per pixel
constexpr int   CPT       = 16;           // channels per thread
constexpr int   PPB       = 16;           // pixels per block
constexpr int   BLOCK     = TPP * PPB;    // 192 (3 waves)
constexpr int   CS_STRIDE = 212;          // swizzled row: swz(191)=211 -> 212 (mult of 4)
constexpr float AON       = 0.0001f / 5.0f;  // alpha/n = 2e-5

__device__ __forceinline__ int swz(int j) { return j + ((j >> 5) << 2); }

__global__ __launch_bounds__(BLOCK, 7) void lrn_kernel(
    const float* __restrict__ x, float* __restrict__ out, int npix) {
  __shared__ __align__(16) float cs[PPB * CS_STRIDE];   // swizzled exclusive prefixes
  __shared__ __align__(16) float tot[PPB * TPP];        // chunk totals

  const int tid = threadIdx.x;
  const int t   = tid % TPP;   // chunk within pixel
  const int p   = tid / TPP;   // pixel within block

  // uniform clamp so duplicate (clamped) blocks just rewrite identical values
  long long pixBase = (long long)blockIdx.x * PPB;
  if (pixBase > npix - PPB) pixBase = npix - PPB;
  const size_t elemBase = (size_t)pixBase * C;

  const float4* __restrict__ xb = (const float4*)(x + elemBase);
  float4* __restrict__ ob       = (float4*)(out + elemBase);

  // ---- step 1: load 16 channels (4 x float4), chunk sum of squares ----
  const float4 v0 = xb[tid * 4 + 0];
  const float4 v1 = xb[tid * 4 + 1];
  const float4 v2 = xb[tid * 4 + 2];
  const float4 v3 = xb[tid * 4 + 3];
  float xr[CPT] = {v0.x, v0.y, v0.z, v0.w, v1.x, v1.y, v1.z, v1.w,
                   v2.x, v2.y, v2.z, v2.w, v3.x, v3.y, v3.z, v3.w};

  float a0 = xr[0] * xr[0], a1 = xr[1] * xr[1], a2 = xr[2] * xr[2], a3 = xr[3] * xr[3];
#pragma unroll
  for (int k = 4; k < CPT; k += 4) {
    a0 = fmaf(xr[k + 0], xr[k + 0], a0);
    a1 = fmaf(xr[k + 1], xr[k + 1], a1);
    a2 = fmaf(xr[k + 2], xr[k + 2], a2);
    a3 = fmaf(xr[k + 3], xr[k + 3], a3);
  }
  tot[tid] = (a0 + a1) + (a2 + a3);
  __syncthreads();

  // ---- step 2: chunk base (sum of totals before t) and pixel total ----
  const float4* tp = (const float4*)&tot[p * TPP];
  const float4 t0 = tp[0], t1 = tp[1], t2 = tp[2];
  const float tv[TPP] = {t0.x, t0.y, t0.z, t0.w, t1.x, t1.y, t1.z, t1.w,
                         t2.x, t2.y, t2.z, t2.w};
  float base = 0.0f, total = 0.0f;
#pragma unroll
  for (int i = 0; i < TPP; ++i) {
    total += tv[i];
    base  += (i < t) ? tv[i] : 0.0f;
  }

  // ---- step 3: global exclusive prefix in regs, vector-write to swizzled LDS ----
  float pre[CPT];
  float run = base;
#pragma unroll
  for (int k = 0; k < CPT; ++k) {
    pre[k] = run;
    run = fmaf(xr[k], xr[k], run);
  }
  float* csp = &cs[p * CS_STRIDE];
#pragma unroll
  for (int g = 0; g < 4; ++g) {
    const int j = t * CPT + g * 4;  // mult of 4; 4-word group never crosses a 32-boundary
    *(float4*)&csp[swz(j)] = make_float4(pre[g * 4], pre[g * 4 + 1],
                                         pre[g * 4 + 2], pre[g * 4 + 3]);
  }
  __syncthreads();

  // ---- head boundary (cs[16t-2], cs[16t-1]) for k=0,1 ----
  float hb0 = 0.0f, hb1 = 0.0f;   // t==0: head=0 -> cs[0]=0
  if (t > 0) {
    const int j = t * CPT - 2;    // even; j and j+1 share a 32-block -> contiguous
    const int s = swz(j);
    hb0 = csp[s];
    hb1 = csp[s + 1];
  }

  // ---- step 4: windowed sums, series scale, store ----
#pragma unroll
  for (int g = 0; g < 4; ++g) {
    float q[4];
#pragma unroll
    for (int kk = 0; kk < 4; ++kk) {
      const int k = g * 4 + kk;
      const int c = t * CPT + k;
      const float csh = (k >= 2) ? pre[k - 2] : (k == 0 ? hb0 : hb1);
      const int e = 2 * c + 3;
      const float cse = (e < C) ? csp[swz(e)] : total;   // c>=95 -> window end = C
      const float eps = (cse - csh) * AON;               // in [0, ~0.005]
      // (1+eps)^-0.75 ~ 1 - 0.75 e + 0.65625 e^2 - 0.6015625 e^3
      const float inv = fmaf(eps, fmaf(eps, fmaf(eps, -0.6015625f, 0.65625f), -0.75f), 1.0f);
      q[kk] = xr[k] * inv;
    }
    ob[tid * 4 + g] = make_float4(q[0], q[1], q[2], q[3]);
  }
}

extern "C" void kernel_launch(void* const* d_in, const int* in_sizes, int n_in,
                              void* d_out, int out_size, void* d_ws, size_t ws_size,
                              hipStream_t stream) {
  const float* x   = (const float*)d_in[0];
  float*       out = (float*)d_out;
  const int npix = in_sizes[0] / C;            // 64*56*56 = 200704 (= 16 * 12544)
  const int grid = (npix + PPB - 1) / PPB;     // 12544
  lrn_kernel<<<grid, BLOCK, 0, stream>>>(x, out, npix);
}

// Round 3
// 261.848 us; speedup vs baseline: 1.2487x; 1.0202x over previous
//
#include <hip/hip_runtime.h>

// LRN (buggy-keras window) on x:(64,56,56,192) fp32 NHWC.
// window for channel c: [max(c-2,0), min(2c+3, C)); scale=(sum*2e-5+1)^0.75; out=x/scale
//
// R3: wave-self-contained decomposition (R2 was phase/barrier latency-bound: all pipes <35%).
// 16 lanes/pixel, 12 channels/lane, 4 pixels/wave, 4 independent waves/block.
// Chunk-total scan: 4x shfl_up(width=16) once per wave. LDS holds ONLY odd prefixes
// (cs[2i+1] at table[i]); gather index for channel c is exactly c+1 (end=2c+3 odd).
// Heads from own regs (pre[k-2]) or one neighbor shfl_up (k=0,1). Single __syncthreads
// (no cross-wave deps -> near-zero wait; vmcnt already drained there).
// (1+e)^-0.75 via cubic series (e<=~0.01 -> err <1e-7 vs thr 0.108).

constexpr int   C    = 192;
constexpr int   LPP  = 16;            // lanes per pixel
constexpr int   CPL  = 12;            // channels per lane
constexpr int   PPW  = 4;             // pixels per wave
constexpr int   WPB  = 4;             // waves per block
constexpr int   PPB  = PPW * WPB;     // 16 pixels per block
constexpr int   BLOCK = 256;
constexpr int   S    = 100;           // odd-table stride per pixel (96 + 4 pad)
constexpr float AON  = 0.0001f / 5.0f;  // alpha/n = 2e-5

__global__ __launch_bounds__(BLOCK, 8) void lrn_kernel(
    const float* __restrict__ x, float* __restrict__ out, int npix) {
  __shared__ __align__(16) float oddcs[WPB * PPW * S];  // 6400 B

  const int tid  = threadIdx.x;
  const int lane = tid & 63;
  const int w    = tid >> 6;
  const int sub  = lane & 15;   // lane within pixel
  const int pl   = lane >> 4;   // pixel within wave

  long long pix = (long long)blockIdx.x * PPB + w * PPW + pl;
  if (pix > npix - 1) pix = npix - 1;   // benign duplicate work; LDS regions stay disjoint

  const float4* __restrict__ xb = (const float4*)(x + (size_t)pix * C);
  float4* __restrict__ ob       = (float4*)(out + (size_t)pix * C);

  // ---- load 12 channels (3 x float4) ----
  const float4 v0 = xb[sub * 3 + 0];
  const float4 v1 = xb[sub * 3 + 1];
  const float4 v2 = xb[sub * 3 + 2];
  float xr[CPL] = {v0.x, v0.y, v0.z, v0.w, v1.x, v1.y, v1.z, v1.w,
                   v2.x, v2.y, v2.z, v2.w};

  // ---- chunk total (2-way split chain) ----
  float ta = 0.0f, tb = 0.0f;
#pragma unroll
  for (int k = 0; k < CPL; k += 2) {
    ta = fmaf(xr[k], xr[k], ta);
    tb = fmaf(xr[k + 1], xr[k + 1], tb);
  }
  const float T = ta + tb;

  // ---- inclusive scan of 16 chunk totals within the pixel's lane group ----
  float incl = T;
#pragma unroll
  for (int off = 1; off < LPP; off <<= 1) {
    const float t = __shfl_up(incl, off, LPP);
    if (sub >= off) incl += t;
  }
  const float base  = incl - T;                 // exclusive: sum of chunks before this lane
  const float total = __shfl(incl, LPP - 1, LPP);  // cs[192]

  // ---- exclusive prefix over own 12 channels ----
  float pre[CPL];
  float run = base;
#pragma unroll
  for (int k = 0; k < CPL; ++k) {
    pre[k] = run;
    run = fmaf(xr[k], xr[k], run);
  }

  // ---- head boundary values for k=0,1 from neighbor lane ----
  float hb0 = __shfl_up(pre[CPL - 2], 1, LPP);  // cs[12*sub - 2]
  float hb1 = __shfl_up(pre[CPL - 1], 1, LPP);  // cs[12*sub - 1]
  if (sub == 0) { hb0 = 0.0f; hb1 = 0.0f; }     // c=0,1 -> head=0 -> cs[0]=0

  // ---- write odd prefixes: cs[2i+1] at tab[i]; lane covers i = 6*sub .. 6*sub+5 ----
  float* tab = &oddcs[(w * PPW + pl) * S];
  {
    float2* tp = (float2*)&tab[6 * sub];        // 8B aligned (24*sub bytes)
    tp[0] = make_float2(pre[1], pre[3]);
    tp[1] = make_float2(pre[5], pre[7]);
    tp[2] = make_float2(pre[9], pre[11]);
  }
  __syncthreads();  // intra-block visibility; waves independent -> near-zero wait

  // ---- windowed sums + series scale + store ----
#pragma unroll
  for (int g = 0; g < 3; ++g) {
    float q[4];
#pragma unroll
    for (int kk = 0; kk < 4; ++kk) {
      const int k = g * 4 + kk;
      const int c = CPL * sub + k;              // channel within pixel
      const float csh = (k >= 2) ? pre[k - 2] : (k == 0 ? hb0 : hb1);
      // end = 2c+3 (odd) -> cs[end] = tab[c+1] when end<192 (c<95), else cs[192]=total
      const float cse = (c < 95) ? tab[c + 1] : total;
      const float eps = (cse - csh) * AON;      // in [0, ~0.01]
      // (1+e)^-0.75 ~= 1 - 0.75e + 0.65625e^2 - 0.6015625e^3
      const float inv = fmaf(eps, fmaf(eps, fmaf(eps, -0.6015625f, 0.65625f), -0.75f), 1.0f);
      q[kk] = xr[k] * inv;
    }
    ob[sub * 3 + g] = make_float4(q[0], q[1], q[2], q[3]);
  }
}

extern "C" void kernel_launch(void* const* d_in, const int* in_sizes, int n_in,
                              void* d_out, int out_size, void* d_ws, size_t ws_size,
                              hipStream_t stream) {
  const float* x   = (const float*)d_in[0];
  float*       out = (float*)d_out;
  const int npix = in_sizes[0] / C;             // 64*56*56 = 200704 (= 16 * 12544)
  const int grid = (npix + PPB - 1) / PPB;      // 12544
  lrn_kernel<<<grid, BLOCK, 0, stream>>>(x, out, npix);
}